// Round 7
// baseline (2517.693 us; speedup 1.0000x reference)
//
#include <hip/hip_runtime.h>

#define HID 16
#define OUTC 4
#define G 128            // nodes per dst-bucket
#define GSH 7            // log2(G)
#define PHSH 16          // src-phase = src >> 16  (<=65536 nodes = <=4MB of mS per phase)
#define CHUNKS 1024      // edge chunks for partition passes
#define PBLK 512         // threads per partition-pass block
#define MAXBINS 8192     // max (bucket,phase) bins supported by LDS tables

__device__ __forceinline__ float relu(float v) { return v > 0.f ? v : 0.f; }

// ---- Pass A: per-(bin,chunk) counts via LDS histogram; bin = dstBucket*NPHASE + srcPhase ----
__global__ void k_cnt(const int* __restrict__ src, const int* __restrict__ dst,
                      int* __restrict__ cnt, int E, int nbins, int nphase) {
    __shared__ int lc[MAXBINS];
    for (int i = threadIdx.x; i < nbins; i += PBLK) lc[i] = 0;
    __syncthreads();
    int c = blockIdx.x;
    int chunk = (E + CHUNKS - 1) / CHUNKS;
    int lo = c * chunk, hi = lo + chunk < E ? lo + chunk : E;
    for (int i = lo + threadIdx.x; i < hi; i += PBLK) {
        int bin = (dst[i] >> GSH) * nphase + ((unsigned)src[i] >> PHSH);
        atomicAdd(lc + bin, 1);
    }
    __syncthreads();
    for (int b = threadIdx.x; b < nbins; b += PBLK)
        cnt[b * CHUNKS + c] = lc[b];
}

// ---- hierarchical exclusive scan over cnt[nbins*CHUNKS] ----
__global__ void k_scanA(int* __restrict__ a, int* __restrict__ bsum, int L) {
    __shared__ int s[1024];
    int i = blockIdx.x * 1024 + threadIdx.x;
    int v = (i < L) ? a[i] : 0;
    s[threadIdx.x] = v; __syncthreads();
    for (int off = 1; off < 1024; off <<= 1) {
        int t = (threadIdx.x >= (unsigned)off) ? s[threadIdx.x - off] : 0;
        __syncthreads();
        s[threadIdx.x] += t;
        __syncthreads();
    }
    if (i < L) a[i] = s[threadIdx.x] - v;               // block-local exclusive
    if (threadIdx.x == 1023) bsum[blockIdx.x] = s[1023];
}

__global__ void k_scanB(int* __restrict__ bsum, int SB) {
    __shared__ int s[1024];
    int carry = 0;
    for (int base = 0; base < SB; base += 1024) {
        int idx = base + threadIdx.x;
        int v = (idx < SB) ? bsum[idx] : 0;
        s[threadIdx.x] = v; __syncthreads();
        for (int off = 1; off < 1024; off <<= 1) {
            int t = (threadIdx.x >= (unsigned)off) ? s[threadIdx.x - off] : 0;
            __syncthreads();
            s[threadIdx.x] += t;
            __syncthreads();
        }
        if (idx < SB) bsum[idx] = carry + s[threadIdx.x] - v;   // exclusive
        carry += s[1023];
        __syncthreads();
    }
}

__global__ void k_scanC(int* __restrict__ a, const int* __restrict__ bsum,
                        int* __restrict__ pOff, int L, int nbins, int E) {
    int i = blockIdx.x * 1024 + threadIdx.x;
    if (i < L) {
        int v = a[i] + bsum[blockIdx.x];
        a[i] = v;
        if ((i & (CHUNKS - 1)) == 0) pOff[i >> 10] = v;   // CHUNKS == 1024
    }
    if (i == 0) pOff[nbins] = E;
}

// ---- Pass B: partition writes with exact offsets (LDS cursors only) ----
__global__ void k_part(const int* __restrict__ src, const int* __restrict__ dst,
                       const int* __restrict__ cnt, unsigned int* __restrict__ rec,
                       int E, int nbins, int nphase) {
    __shared__ int cur[MAXBINS];
    int c = blockIdx.x;
    for (int b = threadIdx.x; b < nbins; b += PBLK) cur[b] = cnt[b * CHUNKS + c];
    __syncthreads();
    int chunk = (E + CHUNKS - 1) / CHUNKS;
    int lo = c * chunk, hi = lo + chunk < E ? lo + chunk : E;
    for (int i = lo + threadIdx.x; i < hi; i += PBLK) {
        int d = dst[i], s = src[i];
        int bin = (d >> GSH) * nphase + ((unsigned)s >> PHSH);
        int p = atomicAdd(cur + bin, 1);                // LDS atomic
        rec[p] = (unsigned int)s | ((unsigned int)(d & (G - 1)) << 18);
    }
}

// ---- per-node degree from bucket records -> dinv ----
__global__ void k_degb(const int* __restrict__ pOff, const unsigned int* __restrict__ rec,
                       float* __restrict__ dinv, int N, int nphase) {
    __shared__ int cnt[G];
    int b = blockIdx.x;
    if (threadIdx.x < G) cnt[threadIdx.x] = 0;
    __syncthreads();
    int beg = pOff[b * nphase], end = pOff[(b + 1) * nphase];
    for (int i = beg + threadIdx.x; i < end; i += 256)
        atomicAdd(cnt + (rec[i] >> 18), 1);             // LDS atomic
    __syncthreads();
    int n = b * G + threadIdx.x;
    if (threadIdx.x < G && n < N)
        dinv[n] = rsqrtf((float)cnt[threadIdx.x] + 1.0f);   // +1 self-loop
}

// ---- mS1[n][c] = x[n] * W1[c] * dinv[n]  (IN_C == 1) ----
__global__ void k_m1(const float* __restrict__ x, const float* __restrict__ W1,
                     const float* __restrict__ dinv, float* __restrict__ m, int N) {
    int t = blockIdx.x * blockDim.x + threadIdx.x;
    if (t < N * HID) {
        int n = t >> 4, c = t & 15;
        m[t] = x[n] * W1[c] * dinv[n];
    }
}

// ---- in-place h -> (h @ W2) * dinv ----
__global__ void k_m2(float4* __restrict__ h4, const float* __restrict__ W2,
                     const float* __restrict__ dinv, int N) {
    __shared__ float hs[64][HID + 1];
    __shared__ float w[HID * HID];
    if (threadIdx.x < HID * HID) w[threadIdx.x] = W2[threadIdx.x];
    int idx = blockIdx.x * 256 + threadIdx.x;          // float4 index
    int n = idx >> 2, q = idx & 3;
    int ln = threadIdx.x >> 2;
    if (n < N) {
        float4 v = h4[idx];
        hs[ln][q * 4 + 0] = v.x; hs[ln][q * 4 + 1] = v.y;
        hs[ln][q * 4 + 2] = v.z; hs[ln][q * 4 + 3] = v.w;
    }
    __syncthreads();
    if (n < N) {
        float dn = dinv[n];
        float4 acc = make_float4(0.f, 0.f, 0.f, 0.f);
        const float* hr = hs[ln];
#pragma unroll
        for (int ci = 0; ci < HID; ++ci) {
            float hv = hr[ci];
            const float* wr = w + ci * HID + q * 4;
            acc.x += hv * wr[0]; acc.y += hv * wr[1];
            acc.z += hv * wr[2]; acc.w += hv * wr[3];
        }
        acc.x *= dn; acc.y *= dn; acc.z *= dn; acc.w *= dn;
        h4[idx] = acc;
    }
}

// ---- phase-blocked bucket aggregation: blockIdx = phase*nb + bucket ----
// All concurrently-resident blocks gather from the same <=4MB src window -> L2 hits.
__global__ void __launch_bounds__(256, 6)
k_agg(const int* __restrict__ pOff, const unsigned int* __restrict__ rec,
      const float4* __restrict__ mS4, float* __restrict__ gagg, int N,
      int nb, int nphase) {
    __shared__ float agg[G * 17];
    int p = blockIdx.x / nb, b = blockIdx.x % nb;
    int bin = b * nphase + p;
    int lo = pOff[bin], hi = pOff[bin + 1];
    for (int i = threadIdx.x; i < G * 17; i += 256) agg[i] = 0.f;
    __syncthreads();
    int q = threadIdx.x & 3;
    int gid = threadIdx.x >> 2;
    int i = lo + gid;
    for (; i + 192 < hi; i += 256) {                    // 4 gathers in flight
        unsigned int r0 = rec[i], r1 = rec[i + 64], r2 = rec[i + 128], r3 = rec[i + 192];
        float4 m0 = mS4[(r0 & 0x3FFFF) * 4 + q];
        float4 m1 = mS4[(r1 & 0x3FFFF) * 4 + q];
        float4 m2 = mS4[(r2 & 0x3FFFF) * 4 + q];
        float4 m3 = mS4[(r3 & 0x3FFFF) * 4 + q];
        float* a0 = agg + (r0 >> 18) * 17 + q * 4;
        atomicAdd(a0 + 0, m0.x); atomicAdd(a0 + 1, m0.y);
        atomicAdd(a0 + 2, m0.z); atomicAdd(a0 + 3, m0.w);
        float* a1 = agg + (r1 >> 18) * 17 + q * 4;
        atomicAdd(a1 + 0, m1.x); atomicAdd(a1 + 1, m1.y);
        atomicAdd(a1 + 2, m1.z); atomicAdd(a1 + 3, m1.w);
        float* a2 = agg + (r2 >> 18) * 17 + q * 4;
        atomicAdd(a2 + 0, m2.x); atomicAdd(a2 + 1, m2.y);
        atomicAdd(a2 + 2, m2.z); atomicAdd(a2 + 3, m2.w);
        float* a3 = agg + (r3 >> 18) * 17 + q * 4;
        atomicAdd(a3 + 0, m3.x); atomicAdd(a3 + 1, m3.y);
        atomicAdd(a3 + 2, m3.z); atomicAdd(a3 + 3, m3.w);
    }
    for (; i < hi; i += 64) {                           // tail
        unsigned int r = rec[i];
        float4 mv = mS4[(r & 0x3FFFF) * 4 + q];
        float* a = agg + (r >> 18) * 17 + q * 4;
        atomicAdd(a + 0, mv.x); atomicAdd(a + 1, mv.y);
        atomicAdd(a + 2, mv.z); atomicAdd(a + 3, mv.w);
    }
    __syncthreads();
    int base = b * G;
    for (int v = threadIdx.x; v < G * HID; v += 256) {  // coalesced line-shared atomics
        int nl = v >> 4, c = v & 15;
        int n = base + nl;
        if (n >= N) break;
        float val = agg[nl * 17 + c];
        if (val != 0.f) atomicAdd(gagg + n * HID + c, val);
    }
}

// ---- epilogue layer1: h = relu((gagg + mS[n]) * dinv[n] + b) ----
__global__ void k_post(const float4* __restrict__ gagg4, const float4* __restrict__ mS4,
                       const float* __restrict__ dinv, const float4* __restrict__ b4,
                       float4* __restrict__ h4, int N) {
    int t = blockIdx.x * blockDim.x + threadIdx.x;
    if (t < N * 4) {
        int n = t >> 2, q = t & 3;
        float dn = dinv[n];
        float4 ag = gagg4[t];
        float4 ms = mS4[t];
        float4 bb = b4[q];
        float4 hv;
        hv.x = relu((ag.x + ms.x) * dn + bb.x);
        hv.y = relu((ag.y + ms.y) * dn + bb.y);
        hv.z = relu((ag.z + ms.z) * dn + bb.z);
        hv.w = relu((ag.w + ms.w) * dn + bb.w);
        h4[t] = hv;
    }
}

// ---- epilogue layer2 + readout ----
__global__ void k_out(const float4* __restrict__ gagg4, const float4* __restrict__ mS4,
                      const float* __restrict__ dinv, const float4* __restrict__ b4,
                      const float* __restrict__ Wl, const float* __restrict__ bl,
                      float* __restrict__ out, int N) {
    __shared__ float hs[64][HID + 1];
    __shared__ float wl[HID * OUTC];
    __shared__ float blv[OUTC];
    if (threadIdx.x < HID * OUTC) wl[threadIdx.x] = Wl[threadIdx.x];
    if (threadIdx.x < OUTC) blv[threadIdx.x] = bl[threadIdx.x];
    int idx = blockIdx.x * 256 + threadIdx.x;          // float4 index
    int n = idx >> 2, q = idx & 3;
    int ln = threadIdx.x >> 2;
    if (n < N) {
        float dn = dinv[n];
        float4 ag = gagg4[idx];
        float4 ms = mS4[idx];
        float4 bb = b4[q];
        hs[ln][q * 4 + 0] = relu((ag.x + ms.x) * dn + bb.x);
        hs[ln][q * 4 + 1] = relu((ag.y + ms.y) * dn + bb.y);
        hs[ln][q * 4 + 2] = relu((ag.z + ms.z) * dn + bb.z);
        hs[ln][q * 4 + 3] = relu((ag.w + ms.w) * dn + bb.w);
    }
    __syncthreads();
    if (n < N) {
        float acc = blv[q];
        const float* hr = hs[ln];
#pragma unroll
        for (int ci = 0; ci < HID; ++ci) acc += hr[ci] * wl[ci * OUTC + q];
        out[n * OUTC + q] = acc;
    }
}

// ---------- launch ----------
static inline size_t alignup(size_t v, size_t a) { return (v + a - 1) & ~(a - 1); }

extern "C" void kernel_launch(void* const* d_in, const int* in_sizes, int n_in,
                              void* d_out, int out_size, void* d_ws, size_t ws_size,
                              hipStream_t stream) {
    const float* x  = (const float*)d_in[0];
    const int* ed   = (const int*)d_in[1];     // int inputs delivered as int32
    const float* W1 = (const float*)d_in[2];
    const float* b1 = (const float*)d_in[3];
    const float* W2 = (const float*)d_in[4];
    const float* b2 = (const float*)d_in[5];
    const float* Wl = (const float*)d_in[6];
    const float* bl = (const float*)d_in[7];
    float* out      = (float*)d_out;

    int N = in_sizes[0];
    int E = in_sizes[1] / 2;
    const int* src = ed;
    const int* dst = ed + E;
    int nb = (N + G - 1) / G;                  // 1563 dst-buckets
    int nphase = (N + (1 << PHSH) - 1) >> PHSH; // 4 src-phases
    int nbins = nb * nphase;                   // 6252 (<= MAXBINS)
    int L = nbins * CHUNKS;                    // count cells (6.4M)
    int SB = (L + 1023) / 1024;

    // workspace (cnt overlays bufA+bufB: both dead until after k_part)
    char* w = (char*)d_ws;
    size_t o = 0;
    float* dinv       = (float*)(w + o); o = alignup(o + (size_t)N * 4, 16);
    int* bsum         = (int*)(w + o);   o = alignup(o + (size_t)SB * 4, 16);
    int* pOff         = (int*)(w + o);   o = alignup(o + ((size_t)nbins + 1) * 4, 16);
    unsigned int* rec = (unsigned int*)(w + o); o = alignup(o + (size_t)E * 4, 16);
    size_t rbytes = (size_t)L * 4;
    size_t bbytes = (size_t)2 * N * HID * 4;
    float* bufA       = (float*)(w + o);
    float* bufB       = bufA + (size_t)N * HID;
    int* cnt          = (int*)bufA;
    o = alignup(o + (rbytes > bbytes ? rbytes : bbytes), 16);
    (void)ws_size;

    int blk = 256;
    int gN16 = (N * HID + blk - 1) / blk;
    int gN4  = (N * 4 + blk - 1) / blk;
    int gNode64 = (N + 63) / 64;

    // counting-sort partition by (dst-bucket, src-phase); no global atomics
    k_cnt<<<CHUNKS, PBLK, 0, stream>>>(src, dst, cnt, E, nbins, nphase);
    k_scanA<<<SB, 1024, 0, stream>>>(cnt, bsum, L);
    k_scanB<<<1, 1024, 0, stream>>>(bsum, SB);
    k_scanC<<<SB, 1024, 0, stream>>>(cnt, bsum, pOff, L, nbins, E);
    k_part<<<CHUNKS, PBLK, 0, stream>>>(src, dst, cnt, rec, E, nbins, nphase);
    k_degb<<<nb, blk, 0, stream>>>(pOff, rec, dinv, N, nphase);

    // layer 1
    k_m1<<<gN16, blk, 0, stream>>>(x, W1, dinv, bufA, N);
    hipMemsetAsync(bufB, 0, (size_t)N * HID * 4, stream);
    k_agg<<<nb * nphase, blk, 0, stream>>>(pOff, rec, (const float4*)bufA, bufB, N, nb, nphase);
    k_post<<<gN4, blk, 0, stream>>>((const float4*)bufB, (const float4*)bufA, dinv,
                                    (const float4*)b1, (float4*)bufA, N);   // bufA = h1

    // layer 2
    k_m2<<<gNode64, blk, 0, stream>>>((float4*)bufA, W2, dinv, N);          // bufA = mS2
    hipMemsetAsync(bufB, 0, (size_t)N * HID * 4, stream);
    k_agg<<<nb * nphase, blk, 0, stream>>>(pOff, rec, (const float4*)bufA, bufB, N, nb, nphase);
    k_out<<<gNode64, blk, 0, stream>>>((const float4*)bufB, (const float4*)bufA, dinv,
                                       (const float4*)b2, Wl, bl, out, N);
}

// Round 8
// 911.956 us; speedup vs baseline: 2.7608x; 2.7608x over previous
//
#include <hip/hip_runtime.h>

#define HID 16
#define OUTC 4
#define G 64             // nodes per dst-bucket
#define GSH 6            // log2(G)
#define CAP 8192         // LDS record buffer per bucket (avg 4096, +64 sigma safe)
#define CHUNKS 1024      // edge chunks for partition passes
#define PBLK 512         // threads per partition-pass block
#define MAXNB 4096       // max buckets supported by LDS tables (need 3125)

__device__ __forceinline__ float relu(float v) { return v > 0.f ? v : 0.f; }

// ---- Pass A: per-(bucket,chunk) counts via LDS histogram (int atomics only) ----
__global__ void k_cnt(const int* __restrict__ dst, int* __restrict__ cnt, int E, int nb) {
    __shared__ int lc[MAXNB];
    for (int i = threadIdx.x; i < nb; i += PBLK) lc[i] = 0;
    __syncthreads();
    int c = blockIdx.x;
    int chunk = (E + CHUNKS - 1) / CHUNKS;
    int lo = c * chunk, hi = lo + chunk < E ? lo + chunk : E;
    for (int i = lo + threadIdx.x; i < hi; i += PBLK)
        atomicAdd(lc + (dst[i] >> GSH), 1);
    __syncthreads();
    for (int b = threadIdx.x; b < nb; b += PBLK)
        cnt[b * CHUNKS + c] = lc[b];
}

// ---- hierarchical exclusive scan over cnt[nb*CHUNKS] ----
__global__ void k_scanA(int* __restrict__ a, int* __restrict__ bsum, int L) {
    __shared__ int s[1024];
    int i = blockIdx.x * 1024 + threadIdx.x;
    int v = (i < L) ? a[i] : 0;
    s[threadIdx.x] = v; __syncthreads();
    for (int off = 1; off < 1024; off <<= 1) {
        int t = (threadIdx.x >= (unsigned)off) ? s[threadIdx.x - off] : 0;
        __syncthreads();
        s[threadIdx.x] += t;
        __syncthreads();
    }
    if (i < L) a[i] = s[threadIdx.x] - v;               // block-local exclusive
    if (threadIdx.x == 1023) bsum[blockIdx.x] = s[1023];
}

__global__ void k_scanB(int* __restrict__ bsum, int SB) {
    __shared__ int s[1024];
    int carry = 0;
    for (int base = 0; base < SB; base += 1024) {
        int idx = base + threadIdx.x;
        int v = (idx < SB) ? bsum[idx] : 0;
        s[threadIdx.x] = v; __syncthreads();
        for (int off = 1; off < 1024; off <<= 1) {
            int t = (threadIdx.x >= (unsigned)off) ? s[threadIdx.x - off] : 0;
            __syncthreads();
            s[threadIdx.x] += t;
            __syncthreads();
        }
        if (idx < SB) bsum[idx] = carry + s[threadIdx.x] - v;   // exclusive
        carry += s[1023];
        __syncthreads();
    }
}

__global__ void k_scanC(int* __restrict__ a, const int* __restrict__ bsum,
                        int* __restrict__ bOff, int L, int nb, int E) {
    int i = blockIdx.x * 1024 + threadIdx.x;
    if (i < L) {
        int v = a[i] + bsum[blockIdx.x];
        a[i] = v;
        if ((i & (CHUNKS - 1)) == 0) bOff[i >> 10] = v;   // CHUNKS == 1024
    }
    if (i == 0) bOff[nb] = E;
}

// ---- Pass B: partition into bucket regions (LDS cursors only) ----
__global__ void k_part(const int* __restrict__ src, const int* __restrict__ dst,
                       const int* __restrict__ cnt, unsigned int* __restrict__ rec,
                       int E, int nb) {
    __shared__ int cur[MAXNB];
    int c = blockIdx.x;
    for (int b = threadIdx.x; b < nb; b += PBLK) cur[b] = cnt[b * CHUNKS + c];
    __syncthreads();
    int chunk = (E + CHUNKS - 1) / CHUNKS;
    int lo = c * chunk, hi = lo + chunk < E ? lo + chunk : E;
    for (int i = lo + threadIdx.x; i < hi; i += PBLK) {
        int d = dst[i], s = src[i];
        int p = atomicAdd(cur + (d >> GSH), 1);         // LDS int atomic
        rec[p] = (unsigned int)s | ((unsigned int)(d & (G - 1)) << 18);
    }
}

// ---- per-bucket counting sort by dst-local -> in-place CSR adjacency + row + dinv ----
__global__ void __launch_bounds__(256) k_sort(const int* __restrict__ bOff,
                                              unsigned int* __restrict__ rec,
                                              float* __restrict__ dinv, int* __restrict__ row,
                                              int N, int nb, int E) {
    __shared__ unsigned int raw[CAP];
    __shared__ int hist[G], cur[G];
    int b = blockIdx.x;
    int beg = bOff[b], end = bOff[b + 1];
    int size = end - beg; if (size > CAP) size = CAP;   // statistically impossible; LDS guard
    for (int i = threadIdx.x; i < size; i += 256) raw[i] = rec[beg + i];
    if (threadIdx.x < G) hist[threadIdx.x] = 0;
    __syncthreads();
    for (int i = threadIdx.x; i < size; i += 256)
        atomicAdd(hist + (raw[i] >> 18), 1);            // LDS int atomic
    __syncthreads();
    if (threadIdx.x < G) {
        int ex = 0;
        for (int j = 0; j < (int)threadIdx.x; ++j) ex += hist[j];   // 64-wide serial scan
        cur[threadIdx.x] = ex;
        int n = b * G + threadIdx.x;
        if (n < N) {
            row[n] = beg + ex;
            dinv[n] = rsqrtf((float)hist[threadIdx.x] + 1.0f);      // +1 self-loop
        }
    }
    if (b == nb - 1 && threadIdx.x == 0) row[N] = E;
    __syncthreads();
    // scatter: reads from LDS copy, writes back into own global range (no hazard)
    for (int i = threadIdx.x; i < size; i += 256) {
        unsigned int r = raw[i];
        int p = atomicAdd(cur + (r >> 18), 1);          // LDS int atomic
        rec[beg + p] = r & 0x3FFFF;                     // adjacency = src id
    }
}

// ---- mS1[n][c] = x[n] * W1[c] * dinv[n]  (IN_C == 1) ----
__global__ void k_m1(const float* __restrict__ x, const float* __restrict__ W1,
                     const float* __restrict__ dinv, float* __restrict__ m, int N) {
    int t = blockIdx.x * blockDim.x + threadIdx.x;
    if (t < N * HID) {
        int n = t >> 4, c = t & 15;
        m[t] = x[n] * W1[c] * dinv[n];
    }
}

// ---- in-place h -> (h @ W2) * dinv ----
__global__ void k_m2(float4* __restrict__ h4, const float* __restrict__ W2,
                     const float* __restrict__ dinv, int N) {
    __shared__ float hs[64][HID + 1];
    __shared__ float w[HID * HID];
    if (threadIdx.x < HID * HID) w[threadIdx.x] = W2[threadIdx.x];
    int idx = blockIdx.x * 256 + threadIdx.x;          // float4 index
    int n = idx >> 2, q = idx & 3;
    int ln = threadIdx.x >> 2;
    if (n < N) {
        float4 v = h4[idx];
        hs[ln][q * 4 + 0] = v.x; hs[ln][q * 4 + 1] = v.y;
        hs[ln][q * 4 + 2] = v.z; hs[ln][q * 4 + 3] = v.w;
    }
    __syncthreads();
    if (n < N) {
        float dn = dinv[n];
        float4 acc = make_float4(0.f, 0.f, 0.f, 0.f);
        const float* hr = hs[ln];
#pragma unroll
        for (int ci = 0; ci < HID; ++ci) {
            float hv = hr[ci];
            const float* wr = w + ci * HID + q * 4;
            acc.x += hv * wr[0]; acc.y += hv * wr[1];
            acc.z += hv * wr[2]; acc.w += hv * wr[3];
        }
        acc.x *= dn; acc.y *= dn; acc.z *= dn; acc.w *= dn;
        h4[idx] = acc;
    }
}

// ---- CSR aggregation, register accumulation, fused epilogue (layer 1) ----
__global__ void __launch_bounds__(256) k_agg1(const int* __restrict__ row,
                                              const unsigned int* __restrict__ adj,
                                              const float* __restrict__ dinv,
                                              const float4* __restrict__ mS4,
                                              const float4* __restrict__ b4,
                                              float4* __restrict__ h4, int N) {
    int dl = threadIdx.x >> 2, q = threadIdx.x & 3;
    int n = blockIdx.x * G + dl;
    if (n >= N) return;
    int i = row[n], end = row[n + 1];
    float4 acc = make_float4(0.f, 0.f, 0.f, 0.f);
    for (; i + 4 <= end; i += 4) {                      // 4 independent gathers in flight
        int s0 = adj[i] * 4 + q, s1 = adj[i + 1] * 4 + q;
        int s2 = adj[i + 2] * 4 + q, s3 = adj[i + 3] * 4 + q;
        float4 v0 = mS4[s0], v1 = mS4[s1], v2 = mS4[s2], v3 = mS4[s3];
        acc.x += v0.x + v1.x + v2.x + v3.x;
        acc.y += v0.y + v1.y + v2.y + v3.y;
        acc.z += v0.z + v1.z + v2.z + v3.z;
        acc.w += v0.w + v1.w + v2.w + v3.w;
    }
    for (; i < end; ++i) {
        float4 v = mS4[adj[i] * 4 + q];
        acc.x += v.x; acc.y += v.y; acc.z += v.z; acc.w += v.w;
    }
    float dn = dinv[n];
    float4 ms = mS4[n * 4 + q];
    float4 bb = b4[q];
    float4 h;
    h.x = relu((acc.x + ms.x) * dn + bb.x);
    h.y = relu((acc.y + ms.y) * dn + bb.y);
    h.z = relu((acc.z + ms.z) * dn + bb.z);
    h.w = relu((acc.w + ms.w) * dn + bb.w);
    h4[n * 4 + q] = h;
}

// ---- CSR aggregation layer 2 fused with readout: out = relu(h2) @ Wl + bl ----
__global__ void __launch_bounds__(256) k_agg2(const int* __restrict__ row,
                                              const unsigned int* __restrict__ adj,
                                              const float* __restrict__ dinv,
                                              const float4* __restrict__ mS4,
                                              const float4* __restrict__ b4,
                                              const float* __restrict__ Wl,
                                              const float* __restrict__ bl,
                                              float* __restrict__ out, int N) {
    __shared__ float hs[G][HID + 1];
    __shared__ float wl[HID * OUTC];
    __shared__ float blv[OUTC];
    if (threadIdx.x < HID * OUTC) wl[threadIdx.x] = Wl[threadIdx.x];
    if (threadIdx.x < OUTC) blv[threadIdx.x] = bl[threadIdx.x];
    int dl = threadIdx.x >> 2, q = threadIdx.x & 3;
    int n = blockIdx.x * G + dl;
    if (n < N) {
        int i = row[n], end = row[n + 1];
        float4 acc = make_float4(0.f, 0.f, 0.f, 0.f);
        for (; i + 4 <= end; i += 4) {
            int s0 = adj[i] * 4 + q, s1 = adj[i + 1] * 4 + q;
            int s2 = adj[i + 2] * 4 + q, s3 = adj[i + 3] * 4 + q;
            float4 v0 = mS4[s0], v1 = mS4[s1], v2 = mS4[s2], v3 = mS4[s3];
            acc.x += v0.x + v1.x + v2.x + v3.x;
            acc.y += v0.y + v1.y + v2.y + v3.y;
            acc.z += v0.z + v1.z + v2.z + v3.z;
            acc.w += v0.w + v1.w + v2.w + v3.w;
        }
        for (; i < end; ++i) {
            float4 v = mS4[adj[i] * 4 + q];
            acc.x += v.x; acc.y += v.y; acc.z += v.z; acc.w += v.w;
        }
        float dn = dinv[n];
        float4 ms = mS4[n * 4 + q];
        float4 bb = b4[q];
        hs[dl][q * 4 + 0] = relu((acc.x + ms.x) * dn + bb.x);
        hs[dl][q * 4 + 1] = relu((acc.y + ms.y) * dn + bb.y);
        hs[dl][q * 4 + 2] = relu((acc.z + ms.z) * dn + bb.z);
        hs[dl][q * 4 + 3] = relu((acc.w + ms.w) * dn + bb.w);
    }
    __syncthreads();
    if (n < N) {   // thread -> (node dl, out-channel q)
        float acc = blv[q];
        const float* hr = hs[dl];
#pragma unroll
        for (int ci = 0; ci < HID; ++ci) acc += hr[ci] * wl[ci * OUTC + q];
        out[n * OUTC + q] = acc;
    }
}

// ---------- launch ----------
static inline size_t alignup(size_t v, size_t a) { return (v + a - 1) & ~(a - 1); }

extern "C" void kernel_launch(void* const* d_in, const int* in_sizes, int n_in,
                              void* d_out, int out_size, void* d_ws, size_t ws_size,
                              hipStream_t stream) {
    const float* x  = (const float*)d_in[0];
    const int* ed   = (const int*)d_in[1];     // int inputs delivered as int32
    const float* W1 = (const float*)d_in[2];
    const float* b1 = (const float*)d_in[3];
    const float* W2 = (const float*)d_in[4];
    const float* b2 = (const float*)d_in[5];
    const float* Wl = (const float*)d_in[6];
    const float* bl = (const float*)d_in[7];
    float* out      = (float*)d_out;

    int N = in_sizes[0];
    int E = in_sizes[1] / 2;
    const int* src = ed;
    const int* dst = ed + E;
    int nb = (N + G - 1) / G;                  // 3125 buckets (<= MAXNB)
    int L = nb * CHUNKS;                       // 3.2M count cells
    int SB = (L + 1023) / 1024;

    // workspace (cnt overlays bufA: dead before k_m1 writes it)
    char* w = (char*)d_ws;
    size_t o = 0;
    float* dinv       = (float*)(w + o); o = alignup(o + (size_t)N * 4, 16);
    int* row          = (int*)(w + o);   o = alignup(o + ((size_t)N + 1) * 4, 16);
    int* bsum         = (int*)(w + o);   o = alignup(o + (size_t)SB * 4, 16);
    int* bOff         = (int*)(w + o);   o = alignup(o + ((size_t)nb + 1) * 4, 16);
    unsigned int* rec = (unsigned int*)(w + o); o = alignup(o + (size_t)E * 4, 16);
    float* bufA       = (float*)(w + o); o = alignup(o + (size_t)N * HID * 4, 16);
    float* bufB       = (float*)(w + o); o = alignup(o + (size_t)N * HID * 4, 16);
    int* cnt          = (int*)bufA;            // L*4 = 12.8MB <= bufA
    (void)ws_size;

    int blk = 256;
    int gN16 = (N * HID + blk - 1) / blk;

    // CSR build: counting-sort partition + per-bucket sort (int LDS atomics only)
    k_cnt<<<CHUNKS, PBLK, 0, stream>>>(dst, cnt, E, nb);
    k_scanA<<<SB, 1024, 0, stream>>>(cnt, bsum, L);
    k_scanB<<<1, 1024, 0, stream>>>(bsum, SB);
    k_scanC<<<SB, 1024, 0, stream>>>(cnt, bsum, bOff, L, nb, E);
    k_part<<<CHUNKS, PBLK, 0, stream>>>(src, dst, cnt, rec, E, nb);
    k_sort<<<nb, 256, 0, stream>>>(bOff, rec, dinv, row, N, nb, E);

    // layer 1
    k_m1<<<gN16, blk, 0, stream>>>(x, W1, dinv, bufA, N);
    k_agg1<<<nb, blk, 0, stream>>>(row, rec, dinv, (const float4*)bufA,
                                   (const float4*)b1, (float4*)bufB, N);

    // layer 2 + readout
    k_m2<<<nb, blk, 0, stream>>>((float4*)bufB, W2, dinv, N);      // bufB = mS2 in place
    k_agg2<<<nb, blk, 0, stream>>>(row, rec, dinv, (const float4*)bufB,
                                   (const float4*)b2, Wl, bl, out, N);
}

// Round 9
// 847.588 us; speedup vs baseline: 2.9704x; 1.0759x over previous
//
#include <hip/hip_runtime.h>

#define HID 16
#define OUTC 4
#define G 64             // nodes per dst-bucket
#define GSH 6            // log2(G)
#define CAP 5120         // LDS record buffer per bucket (avg 4096, +16 sigma)
#define KEYSH 13         // src subphase granule: 8192 nodes = 512KB of mS
#define SUBK 32          // 2^(18-KEYSH) subphases
#define KB (G * SUBK)    // 2048 sort bins
#define CHUNKS 1024      // edge chunks for partition passes
#define PBLK 512         // threads per partition-pass block
#define MAXNB 4096       // max buckets supported by LDS tables (need 3125)

__device__ __forceinline__ float relu(float v) { return v > 0.f ? v : 0.f; }

// ---- Pass A: per-(bucket,chunk) counts via LDS histogram (int atomics only) ----
__global__ void k_cnt(const int* __restrict__ dst, int* __restrict__ cnt, int E, int nb) {
    __shared__ int lc[MAXNB];
    for (int i = threadIdx.x; i < nb; i += PBLK) lc[i] = 0;
    __syncthreads();
    int c = blockIdx.x;
    int chunk = (E + CHUNKS - 1) / CHUNKS;
    int lo = c * chunk, hi = lo + chunk < E ? lo + chunk : E;
    for (int i = lo + threadIdx.x; i < hi; i += PBLK)
        atomicAdd(lc + (dst[i] >> GSH), 1);
    __syncthreads();
    for (int b = threadIdx.x; b < nb; b += PBLK)
        cnt[b * CHUNKS + c] = lc[b];
}

// ---- hierarchical exclusive scan over cnt[nb*CHUNKS] ----
__global__ void k_scanA(int* __restrict__ a, int* __restrict__ bsum, int L) {
    __shared__ int s[1024];
    int i = blockIdx.x * 1024 + threadIdx.x;
    int v = (i < L) ? a[i] : 0;
    s[threadIdx.x] = v; __syncthreads();
    for (int off = 1; off < 1024; off <<= 1) {
        int t = (threadIdx.x >= (unsigned)off) ? s[threadIdx.x - off] : 0;
        __syncthreads();
        s[threadIdx.x] += t;
        __syncthreads();
    }
    if (i < L) a[i] = s[threadIdx.x] - v;               // block-local exclusive
    if (threadIdx.x == 1023) bsum[blockIdx.x] = s[1023];
}

__global__ void k_scanB(int* __restrict__ bsum, int SB) {
    __shared__ int s[1024];
    int carry = 0;
    for (int base = 0; base < SB; base += 1024) {
        int idx = base + threadIdx.x;
        int v = (idx < SB) ? bsum[idx] : 0;
        s[threadIdx.x] = v; __syncthreads();
        for (int off = 1; off < 1024; off <<= 1) {
            int t = (threadIdx.x >= (unsigned)off) ? s[threadIdx.x - off] : 0;
            __syncthreads();
            s[threadIdx.x] += t;
            __syncthreads();
        }
        if (idx < SB) bsum[idx] = carry + s[threadIdx.x] - v;   // exclusive
        carry += s[1023];
        __syncthreads();
    }
}

__global__ void k_scanC(int* __restrict__ a, const int* __restrict__ bsum,
                        int* __restrict__ bOff, int L, int nb, int E) {
    int i = blockIdx.x * 1024 + threadIdx.x;
    if (i < L) {
        int v = a[i] + bsum[blockIdx.x];
        a[i] = v;
        if ((i & (CHUNKS - 1)) == 0) bOff[i >> 10] = v;   // CHUNKS == 1024
    }
    if (i == 0) bOff[nb] = E;
}

// ---- Pass B: partition into bucket regions (LDS cursors only) ----
__global__ void k_part(const int* __restrict__ src, const int* __restrict__ dst,
                       const int* __restrict__ cnt, unsigned int* __restrict__ rec,
                       int E, int nb) {
    __shared__ int cur[MAXNB];
    int c = blockIdx.x;
    for (int b = threadIdx.x; b < nb; b += PBLK) cur[b] = cnt[b * CHUNKS + c];
    __syncthreads();
    int chunk = (E + CHUNKS - 1) / CHUNKS;
    int lo = c * chunk, hi = lo + chunk < E ? lo + chunk : E;
    for (int i = lo + threadIdx.x; i < hi; i += PBLK) {
        int d = dst[i], s = src[i];
        int p = atomicAdd(cur + (d >> GSH), 1);         // LDS int atomic
        rec[p] = (unsigned int)s | ((unsigned int)(d & (G - 1)) << 18);
    }
}

// ---- per-bucket counting sort by (dst_local, src>>KEYSH) -> CSR adjacency with
//      ascending-src-window order per node; also emits row + dinv ----
__global__ void __launch_bounds__(256) k_sort(const int* __restrict__ bOff,
                                              unsigned int* __restrict__ rec,
                                              float* __restrict__ dinv, int* __restrict__ row,
                                              int N, int nb, int E) {
    __shared__ unsigned int raw[CAP];
    __shared__ int hist[KB], cur[KB];
    __shared__ int s[256];
    int b = blockIdx.x;
    int beg = bOff[b], end = bOff[b + 1];
    int size = end - beg; if (size > CAP) size = CAP;    // statistically impossible; LDS guard
    for (int i = threadIdx.x; i < size; i += 256) raw[i] = rec[beg + i];
    for (int k = threadIdx.x; k < KB; k += 256) hist[k] = 0;
    __syncthreads();
    for (int i = threadIdx.x; i < size; i += 256) {
        unsigned int r = raw[i];
        int key = (int)((r >> 18) << 5) | (int)((r & 0x3FFFF) >> KEYSH);
        atomicAdd(hist + key, 1);                       // LDS int atomic
    }
    __syncthreads();
    // exclusive scan of hist[KB]: 256 threads x 8 bins each
    int t = threadIdx.x;
    int psum = 0;
#pragma unroll
    for (int j = 0; j < 8; ++j) psum += hist[t * 8 + j];
    s[t] = psum; __syncthreads();
    for (int off = 1; off < 256; off <<= 1) {
        int v = (t >= off) ? s[t - off] : 0;
        __syncthreads();
        s[t] += v;
        __syncthreads();
    }
    int ex = s[t] - psum;                               // exclusive base of this thread's bins
#pragma unroll
    for (int j = 0; j < 8; ++j) {
        int h = hist[t * 8 + j];
        cur[t * 8 + j] = ex;
        ex += h;
    }
    __syncthreads();
    // row + dinv (read cur before scatter mutates it)
    if (t < G) {
        int n = b * G + t;
        if (n < N) {
            row[n] = beg + cur[t << 5];                 // start of node's first subkey
            int deg = 0;
#pragma unroll
            for (int j = 0; j < SUBK; ++j) deg += hist[(t << 5) + j];
            dinv[n] = rsqrtf((float)deg + 1.0f);        // +1 self-loop
        }
    }
    if (b == nb - 1 && t == 0) row[N] = E;
    __syncthreads();
    // scatter: reads LDS copy, writes into own global range (no hazard)
    for (int i = t; i < size; i += 256) {
        unsigned int r = raw[i];
        int key = (int)((r >> 18) << 5) | (int)((r & 0x3FFFF) >> KEYSH);
        int p = atomicAdd(cur + key, 1);                // LDS int atomic
        rec[beg + p] = r & 0x3FFFF;                     // adjacency = src id
    }
}

// ---- mS1[n][c] = x[n] * W1[c] * dinv[n]  (IN_C == 1) ----
__global__ void k_m1(const float* __restrict__ x, const float* __restrict__ W1,
                     const float* __restrict__ dinv, float* __restrict__ m, int N) {
    int t = blockIdx.x * blockDim.x + threadIdx.x;
    if (t < N * HID) {
        int n = t >> 4, c = t & 15;
        m[t] = x[n] * W1[c] * dinv[n];
    }
}

// ---- in-place h -> (h @ W2) * dinv ----
__global__ void k_m2(float4* __restrict__ h4, const float* __restrict__ W2,
                     const float* __restrict__ dinv, int N) {
    __shared__ float hs[64][HID + 1];
    __shared__ float w[HID * HID];
    if (threadIdx.x < HID * HID) w[threadIdx.x] = W2[threadIdx.x];
    int idx = blockIdx.x * 256 + threadIdx.x;          // float4 index
    int n = idx >> 2, q = idx & 3;
    int ln = threadIdx.x >> 2;
    if (n < N) {
        float4 v = h4[idx];
        hs[ln][q * 4 + 0] = v.x; hs[ln][q * 4 + 1] = v.y;
        hs[ln][q * 4 + 2] = v.z; hs[ln][q * 4 + 3] = v.w;
    }
    __syncthreads();
    if (n < N) {
        float dn = dinv[n];
        float4 acc = make_float4(0.f, 0.f, 0.f, 0.f);
        const float* hr = hs[ln];
#pragma unroll
        for (int ci = 0; ci < HID; ++ci) {
            float hv = hr[ci];
            const float* wr = w + ci * HID + q * 4;
            acc.x += hv * wr[0]; acc.y += hv * wr[1];
            acc.z += hv * wr[2]; acc.w += hv * wr[3];
        }
        acc.x *= dn; acc.y *= dn; acc.z *= dn; acc.w *= dn;
        h4[idx] = acc;
    }
}

// ---- CSR aggregation, register accumulation, fused epilogue (layer 1) ----
__global__ void __launch_bounds__(256) k_agg1(const int* __restrict__ row,
                                              const unsigned int* __restrict__ adj,
                                              const float* __restrict__ dinv,
                                              const float4* __restrict__ mS4,
                                              const float4* __restrict__ b4,
                                              float4* __restrict__ h4, int N) {
    int dl = threadIdx.x >> 2, q = threadIdx.x & 3;
    int n = blockIdx.x * G + dl;
    if (n >= N) return;
    int i = row[n], end = row[n + 1];
    float4 acc = make_float4(0.f, 0.f, 0.f, 0.f);
    for (; i + 4 <= end; i += 4) {                      // 4 independent gathers in flight
        int s0 = adj[i] * 4 + q, s1 = adj[i + 1] * 4 + q;
        int s2 = adj[i + 2] * 4 + q, s3 = adj[i + 3] * 4 + q;
        float4 v0 = mS4[s0], v1 = mS4[s1], v2 = mS4[s2], v3 = mS4[s3];
        acc.x += v0.x + v1.x + v2.x + v3.x;
        acc.y += v0.y + v1.y + v2.y + v3.y;
        acc.z += v0.z + v1.z + v2.z + v3.z;
        acc.w += v0.w + v1.w + v2.w + v3.w;
    }
    for (; i < end; ++i) {
        float4 v = mS4[adj[i] * 4 + q];
        acc.x += v.x; acc.y += v.y; acc.z += v.z; acc.w += v.w;
    }
    float dn = dinv[n];
    float4 ms = mS4[n * 4 + q];
    float4 bb = b4[q];
    float4 h;
    h.x = relu((acc.x + ms.x) * dn + bb.x);
    h.y = relu((acc.y + ms.y) * dn + bb.y);
    h.z = relu((acc.z + ms.z) * dn + bb.z);
    h.w = relu((acc.w + ms.w) * dn + bb.w);
    h4[n * 4 + q] = h;
}

// ---- CSR aggregation layer 2 fused with readout: out = relu(h2) @ Wl + bl ----
__global__ void __launch_bounds__(256) k_agg2(const int* __restrict__ row,
                                              const unsigned int* __restrict__ adj,
                                              const float* __restrict__ dinv,
                                              const float4* __restrict__ mS4,
                                              const float4* __restrict__ b4,
                                              const float* __restrict__ Wl,
                                              const float* __restrict__ bl,
                                              float* __restrict__ out, int N) {
    __shared__ float hs[G][HID + 1];
    __shared__ float wl[HID * OUTC];
    __shared__ float blv[OUTC];
    if (threadIdx.x < HID * OUTC) wl[threadIdx.x] = Wl[threadIdx.x];
    if (threadIdx.x < OUTC) blv[threadIdx.x] = bl[threadIdx.x];
    int dl = threadIdx.x >> 2, q = threadIdx.x & 3;
    int n = blockIdx.x * G + dl;
    if (n < N) {
        int i = row[n], end = row[n + 1];
        float4 acc = make_float4(0.f, 0.f, 0.f, 0.f);
        for (; i + 4 <= end; i += 4) {
            int s0 = adj[i] * 4 + q, s1 = adj[i + 1] * 4 + q;
            int s2 = adj[i + 2] * 4 + q, s3 = adj[i + 3] * 4 + q;
            float4 v0 = mS4[s0], v1 = mS4[s1], v2 = mS4[s2], v3 = mS4[s3];
            acc.x += v0.x + v1.x + v2.x + v3.x;
            acc.y += v0.y + v1.y + v2.y + v3.y;
            acc.z += v0.z + v1.z + v2.z + v3.z;
            acc.w += v0.w + v1.w + v2.w + v3.w;
        }
        for (; i < end; ++i) {
            float4 v = mS4[adj[i] * 4 + q];
            acc.x += v.x; acc.y += v.y; acc.z += v.z; acc.w += v.w;
        }
        float dn = dinv[n];
        float4 ms = mS4[n * 4 + q];
        float4 bb = b4[q];
        hs[dl][q * 4 + 0] = relu((acc.x + ms.x) * dn + bb.x);
        hs[dl][q * 4 + 1] = relu((acc.y + ms.y) * dn + bb.y);
        hs[dl][q * 4 + 2] = relu((acc.z + ms.z) * dn + bb.z);
        hs[dl][q * 4 + 3] = relu((acc.w + ms.w) * dn + bb.w);
    }
    __syncthreads();
    if (n < N) {   // thread -> (node dl, out-channel q)
        float acc = blv[q];
        const float* hr = hs[dl];
#pragma unroll
        for (int ci = 0; ci < HID; ++ci) acc += hr[ci] * wl[ci * OUTC + q];
        out[n * OUTC + q] = acc;
    }
}

// ---------- launch ----------
static inline size_t alignup(size_t v, size_t a) { return (v + a - 1) & ~(a - 1); }

extern "C" void kernel_launch(void* const* d_in, const int* in_sizes, int n_in,
                              void* d_out, int out_size, void* d_ws, size_t ws_size,
                              hipStream_t stream) {
    const float* x  = (const float*)d_in[0];
    const int* ed   = (const int*)d_in[1];     // int inputs delivered as int32
    const float* W1 = (const float*)d_in[2];
    const float* b1 = (const float*)d_in[3];
    const float* W2 = (const float*)d_in[4];
    const float* b2 = (const float*)d_in[5];
    const float* Wl = (const float*)d_in[6];
    const float* bl = (const float*)d_in[7];
    float* out      = (float*)d_out;

    int N = in_sizes[0];
    int E = in_sizes[1] / 2;
    const int* src = ed;
    const int* dst = ed + E;
    int nb = (N + G - 1) / G;                  // 3125 buckets (<= MAXNB)
    int L = nb * CHUNKS;                       // 3.2M count cells
    int SB = (L + 1023) / 1024;

    // workspace (cnt overlays bufA: dead before k_m1 writes it)
    char* w = (char*)d_ws;
    size_t o = 0;
    float* dinv       = (float*)(w + o); o = alignup(o + (size_t)N * 4, 16);
    int* row          = (int*)(w + o);   o = alignup(o + ((size_t)N + 1) * 4, 16);
    int* bsum         = (int*)(w + o);   o = alignup(o + (size_t)SB * 4, 16);
    int* bOff         = (int*)(w + o);   o = alignup(o + ((size_t)nb + 1) * 4, 16);
    unsigned int* rec = (unsigned int*)(w + o); o = alignup(o + (size_t)E * 4, 16);
    float* bufA       = (float*)(w + o); o = alignup(o + (size_t)N * HID * 4, 16);
    float* bufB       = (float*)(w + o); o = alignup(o + (size_t)N * HID * 4, 16);
    int* cnt          = (int*)bufA;            // L*4 = 12.8MB <= bufA
    (void)ws_size;

    int blk = 256;
    int gN16 = (N * HID + blk - 1) / blk;

    // CSR build: counting-sort partition + per-bucket (dst, src-window) sort
    k_cnt<<<CHUNKS, PBLK, 0, stream>>>(dst, cnt, E, nb);
    k_scanA<<<SB, 1024, 0, stream>>>(cnt, bsum, L);
    k_scanB<<<1, 1024, 0, stream>>>(bsum, SB);
    k_scanC<<<SB, 1024, 0, stream>>>(cnt, bsum, bOff, L, nb, E);
    k_part<<<CHUNKS, PBLK, 0, stream>>>(src, dst, cnt, rec, E, nb);
    k_sort<<<nb, 256, 0, stream>>>(bOff, rec, dinv, row, N, nb, E);

    // layer 1
    k_m1<<<gN16, blk, 0, stream>>>(x, W1, dinv, bufA, N);
    k_agg1<<<nb, blk, 0, stream>>>(row, rec, dinv, (const float4*)bufA,
                                   (const float4*)b1, (float4*)bufB, N);

    // layer 2 + readout
    k_m2<<<nb, blk, 0, stream>>>((float4*)bufB, W2, dinv, N);      // bufB = mS2 in place
    k_agg2<<<nb, blk, 0, stream>>>(row, rec, dinv, (const float4*)bufB,
                                   (const float4*)b2, Wl, bl, out, N);
}

// Round 10
// 798.990 us; speedup vs baseline: 3.1511x; 1.0608x over previous
//
#include <hip/hip_runtime.h>

#define HID 16
#define OUTC 4
#define G 64             // nodes per dst-bucket
#define GSH 6            // log2(G)
#define CAP 5120         // LDS record buffer per bucket (avg 4096, +16 sigma)
#define KEYSH 13         // src subphase granule: 8192 nodes = 512KB of mS
#define SUBK 32          // 2^(18-KEYSH) subphases
#define KB (G * SUBK)    // 2048 sort bins
#define CHUNKS 256       // edge chunks: E/(CHUNKS*nb) ~= 16 records = 64B per cell
#define PBLK 512         // threads per partition-pass block
#define MAXNB 4096       // max buckets supported by LDS tables (need 3125)

__device__ __forceinline__ float relu(float v) { return v > 0.f ? v : 0.f; }

// ---- Pass A: per-(bucket,chunk) counts via LDS histogram (int atomics only) ----
__global__ void k_cnt(const int* __restrict__ dst, int* __restrict__ cnt, int E, int nb) {
    __shared__ int lc[MAXNB];
    for (int i = threadIdx.x; i < nb; i += PBLK) lc[i] = 0;
    __syncthreads();
    int c = blockIdx.x;
    int chunk = (E + CHUNKS - 1) / CHUNKS;
    int lo = c * chunk, hi = lo + chunk < E ? lo + chunk : E;
    for (int i = lo + threadIdx.x; i < hi; i += PBLK)
        atomicAdd(lc + (dst[i] >> GSH), 1);
    __syncthreads();
    for (int b = threadIdx.x; b < nb; b += PBLK)
        cnt[b * CHUNKS + c] = lc[b];
}

// ---- hierarchical exclusive scan over cnt[nb*CHUNKS] ----
__global__ void k_scanA(int* __restrict__ a, int* __restrict__ bsum, int L) {
    __shared__ int s[1024];
    int i = blockIdx.x * 1024 + threadIdx.x;
    int v = (i < L) ? a[i] : 0;
    s[threadIdx.x] = v; __syncthreads();
    for (int off = 1; off < 1024; off <<= 1) {
        int t = (threadIdx.x >= (unsigned)off) ? s[threadIdx.x - off] : 0;
        __syncthreads();
        s[threadIdx.x] += t;
        __syncthreads();
    }
    if (i < L) a[i] = s[threadIdx.x] - v;               // block-local exclusive
    if (threadIdx.x == 1023) bsum[blockIdx.x] = s[1023];
}

__global__ void k_scanB(int* __restrict__ bsum, int SB) {
    __shared__ int s[1024];
    int carry = 0;
    for (int base = 0; base < SB; base += 1024) {
        int idx = base + threadIdx.x;
        int v = (idx < SB) ? bsum[idx] : 0;
        s[threadIdx.x] = v; __syncthreads();
        for (int off = 1; off < 1024; off <<= 1) {
            int t = (threadIdx.x >= (unsigned)off) ? s[threadIdx.x - off] : 0;
            __syncthreads();
            s[threadIdx.x] += t;
            __syncthreads();
        }
        if (idx < SB) bsum[idx] = carry + s[threadIdx.x] - v;   // exclusive
        carry += s[1023];
        __syncthreads();
    }
}

__global__ void k_scanC(int* __restrict__ a, const int* __restrict__ bsum,
                        int* __restrict__ bOff, int L, int nb, int E) {
    int i = blockIdx.x * 1024 + threadIdx.x;
    if (i < L) {
        int v = a[i] + bsum[blockIdx.x];
        a[i] = v;
        if ((i & (CHUNKS - 1)) == 0) bOff[i / CHUNKS] = v;
    }
    if (i == 0) bOff[nb] = E;
}

// ---- Pass B: partition into bucket regions (LDS cursors only) ----
__global__ void k_part(const int* __restrict__ src, const int* __restrict__ dst,
                       const int* __restrict__ cnt, unsigned int* __restrict__ rec,
                       int E, int nb) {
    __shared__ int cur[MAXNB];
    int c = blockIdx.x;
    for (int b = threadIdx.x; b < nb; b += PBLK) cur[b] = cnt[b * CHUNKS + c];
    __syncthreads();
    int chunk = (E + CHUNKS - 1) / CHUNKS;
    int lo = c * chunk, hi = lo + chunk < E ? lo + chunk : E;
    for (int i = lo + threadIdx.x; i < hi; i += PBLK) {
        int d = dst[i], s = src[i];
        int p = atomicAdd(cur + (d >> GSH), 1);         // LDS int atomic
        rec[p] = (unsigned int)s | ((unsigned int)(d & (G - 1)) << 18);
    }
}

// ---- per-bucket counting sort by (dst_local, src>>KEYSH) -> CSR adjacency with
//      ascending-src-window order per node; also emits row + dinv ----
__global__ void __launch_bounds__(256) k_sort(const int* __restrict__ bOff,
                                              unsigned int* __restrict__ rec,
                                              float* __restrict__ dinv, int* __restrict__ row,
                                              int N, int nb, int E) {
    __shared__ unsigned int raw[CAP];
    __shared__ int hist[KB], cur[KB];
    __shared__ int s[256];
    int b = blockIdx.x;
    int beg = bOff[b], end = bOff[b + 1];
    int size = end - beg; if (size > CAP) size = CAP;    // statistically impossible; LDS guard
    for (int i = threadIdx.x; i < size; i += 256) raw[i] = rec[beg + i];
    for (int k = threadIdx.x; k < KB; k += 256) hist[k] = 0;
    __syncthreads();
    for (int i = threadIdx.x; i < size; i += 256) {
        unsigned int r = raw[i];
        int key = (int)((r >> 18) << 5) | (int)((r & 0x3FFFF) >> KEYSH);
        atomicAdd(hist + key, 1);                       // LDS int atomic
    }
    __syncthreads();
    // exclusive scan of hist[KB]: 256 threads x 8 bins each
    int t = threadIdx.x;
    int psum = 0;
#pragma unroll
    for (int j = 0; j < 8; ++j) psum += hist[t * 8 + j];
    s[t] = psum; __syncthreads();
    for (int off = 1; off < 256; off <<= 1) {
        int v = (t >= off) ? s[t - off] : 0;
        __syncthreads();
        s[t] += v;
        __syncthreads();
    }
    int ex = s[t] - psum;                               // exclusive base of this thread's bins
#pragma unroll
    for (int j = 0; j < 8; ++j) {
        int h = hist[t * 8 + j];
        cur[t * 8 + j] = ex;
        ex += h;
    }
    __syncthreads();
    // row + dinv (read cur before scatter mutates it)
    if (t < G) {
        int n = b * G + t;
        if (n < N) {
            row[n] = beg + cur[t << 5];                 // start of node's first subkey
            int deg = 0;
#pragma unroll
            for (int j = 0; j < SUBK; ++j) deg += hist[(t << 5) + j];
            dinv[n] = rsqrtf((float)deg + 1.0f);        // +1 self-loop
        }
    }
    if (b == nb - 1 && t == 0) row[N] = E;
    __syncthreads();
    // scatter: reads LDS copy, writes into own global range (no hazard)
    for (int i = t; i < size; i += 256) {
        unsigned int r = raw[i];
        int key = (int)((r >> 18) << 5) | (int)((r & 0x3FFFF) >> KEYSH);
        int p = atomicAdd(cur + key, 1);                // LDS int atomic
        rec[beg + p] = r & 0x3FFFF;                     // adjacency = src id
    }
}

// ---- mS1[n][c] = x[n] * W1[c] * dinv[n]  (IN_C == 1) ----
__global__ void k_m1(const float* __restrict__ x, const float* __restrict__ W1,
                     const float* __restrict__ dinv, float* __restrict__ m, int N) {
    int t = blockIdx.x * blockDim.x + threadIdx.x;
    if (t < N * HID) {
        int n = t >> 4, c = t & 15;
        m[t] = x[n] * W1[c] * dinv[n];
    }
}

// ---- in-place h -> (h @ W2) * dinv ----
__global__ void k_m2(float4* __restrict__ h4, const float* __restrict__ W2,
                     const float* __restrict__ dinv, int N) {
    __shared__ float hs[64][HID + 1];
    __shared__ float w[HID * HID];
    if (threadIdx.x < HID * HID) w[threadIdx.x] = W2[threadIdx.x];
    int idx = blockIdx.x * 256 + threadIdx.x;          // float4 index
    int n = idx >> 2, q = idx & 3;
    int ln = threadIdx.x >> 2;
    if (n < N) {
        float4 v = h4[idx];
        hs[ln][q * 4 + 0] = v.x; hs[ln][q * 4 + 1] = v.y;
        hs[ln][q * 4 + 2] = v.z; hs[ln][q * 4 + 3] = v.w;
    }
    __syncthreads();
    if (n < N) {
        float dn = dinv[n];
        float4 acc = make_float4(0.f, 0.f, 0.f, 0.f);
        const float* hr = hs[ln];
#pragma unroll
        for (int ci = 0; ci < HID; ++ci) {
            float hv = hr[ci];
            const float* wr = w + ci * HID + q * 4;
            acc.x += hv * wr[0]; acc.y += hv * wr[1];
            acc.z += hv * wr[2]; acc.w += hv * wr[3];
        }
        acc.x *= dn; acc.y *= dn; acc.z *= dn; acc.w *= dn;
        h4[idx] = acc;
    }
}

// ---- CSR aggregation, register accumulation, fused epilogue (layer 1) ----
__global__ void __launch_bounds__(256) k_agg1(const int* __restrict__ row,
                                              const unsigned int* __restrict__ adj,
                                              const float* __restrict__ dinv,
                                              const float4* __restrict__ mS4,
                                              const float4* __restrict__ b4,
                                              float4* __restrict__ h4, int N) {
    int dl = threadIdx.x >> 2, q = threadIdx.x & 3;
    int n = blockIdx.x * G + dl;
    if (n >= N) return;
    int i = row[n], end = row[n + 1];
    float4 acc = make_float4(0.f, 0.f, 0.f, 0.f);
    for (; i + 4 <= end; i += 4) {                      // 4 independent gathers in flight
        int s0 = adj[i] * 4 + q, s1 = adj[i + 1] * 4 + q;
        int s2 = adj[i + 2] * 4 + q, s3 = adj[i + 3] * 4 + q;
        float4 v0 = mS4[s0], v1 = mS4[s1], v2 = mS4[s2], v3 = mS4[s3];
        acc.x += v0.x + v1.x + v2.x + v3.x;
        acc.y += v0.y + v1.y + v2.y + v3.y;
        acc.z += v0.z + v1.z + v2.z + v3.z;
        acc.w += v0.w + v1.w + v2.w + v3.w;
    }
    for (; i < end; ++i) {
        float4 v = mS4[adj[i] * 4 + q];
        acc.x += v.x; acc.y += v.y; acc.z += v.z; acc.w += v.w;
    }
    float dn = dinv[n];
    float4 ms = mS4[n * 4 + q];
    float4 bb = b4[q];
    float4 h;
    h.x = relu((acc.x + ms.x) * dn + bb.x);
    h.y = relu((acc.y + ms.y) * dn + bb.y);
    h.z = relu((acc.z + ms.z) * dn + bb.z);
    h.w = relu((acc.w + ms.w) * dn + bb.w);
    h4[n * 4 + q] = h;
}

// ---- CSR aggregation layer 2 fused with readout: out = relu(h2) @ Wl + bl ----
__global__ void __launch_bounds__(256) k_agg2(const int* __restrict__ row,
                                              const unsigned int* __restrict__ adj,
                                              const float* __restrict__ dinv,
                                              const float4* __restrict__ mS4,
                                              const float4* __restrict__ b4,
                                              const float* __restrict__ Wl,
                                              const float* __restrict__ bl,
                                              float* __restrict__ out, int N) {
    __shared__ float hs[G][HID + 1];
    __shared__ float wl[HID * OUTC];
    __shared__ float blv[OUTC];
    if (threadIdx.x < HID * OUTC) wl[threadIdx.x] = Wl[threadIdx.x];
    if (threadIdx.x < OUTC) blv[threadIdx.x] = bl[threadIdx.x];
    int dl = threadIdx.x >> 2, q = threadIdx.x & 3;
    int n = blockIdx.x * G + dl;
    if (n < N) {
        int i = row[n], end = row[n + 1];
        float4 acc = make_float4(0.f, 0.f, 0.f, 0.f);
        for (; i + 4 <= end; i += 4) {
            int s0 = adj[i] * 4 + q, s1 = adj[i + 1] * 4 + q;
            int s2 = adj[i + 2] * 4 + q, s3 = adj[i + 3] * 4 + q;
            float4 v0 = mS4[s0], v1 = mS4[s1], v2 = mS4[s2], v3 = mS4[s3];
            acc.x += v0.x + v1.x + v2.x + v3.x;
            acc.y += v0.y + v1.y + v2.y + v3.y;
            acc.z += v0.z + v1.z + v2.z + v3.z;
            acc.w += v0.w + v1.w + v2.w + v3.w;
        }
        for (; i < end; ++i) {
            float4 v = mS4[adj[i] * 4 + q];
            acc.x += v.x; acc.y += v.y; acc.z += v.z; acc.w += v.w;
        }
        float dn = dinv[n];
        float4 ms = mS4[n * 4 + q];
        float4 bb = b4[q];
        hs[dl][q * 4 + 0] = relu((acc.x + ms.x) * dn + bb.x);
        hs[dl][q * 4 + 1] = relu((acc.y + ms.y) * dn + bb.y);
        hs[dl][q * 4 + 2] = relu((acc.z + ms.z) * dn + bb.z);
        hs[dl][q * 4 + 3] = relu((acc.w + ms.w) * dn + bb.w);
    }
    __syncthreads();
    if (n < N) {   // thread -> (node dl, out-channel q)
        float acc = blv[q];
        const float* hr = hs[dl];
#pragma unroll
        for (int ci = 0; ci < HID; ++ci) acc += hr[ci] * wl[ci * OUTC + q];
        out[n * OUTC + q] = acc;
    }
}

// ---------- launch ----------
static inline size_t alignup(size_t v, size_t a) { return (v + a - 1) & ~(a - 1); }

extern "C" void kernel_launch(void* const* d_in, const int* in_sizes, int n_in,
                              void* d_out, int out_size, void* d_ws, size_t ws_size,
                              hipStream_t stream) {
    const float* x  = (const float*)d_in[0];
    const int* ed   = (const int*)d_in[1];     // int inputs delivered as int32
    const float* W1 = (const float*)d_in[2];
    const float* b1 = (const float*)d_in[3];
    const float* W2 = (const float*)d_in[4];
    const float* b2 = (const float*)d_in[5];
    const float* Wl = (const float*)d_in[6];
    const float* bl = (const float*)d_in[7];
    float* out      = (float*)d_out;

    int N = in_sizes[0];
    int E = in_sizes[1] / 2;
    const int* src = ed;
    const int* dst = ed + E;
    int nb = (N + G - 1) / G;                  // 3125 buckets (<= MAXNB)
    int L = nb * CHUNKS;                       // 800K count cells
    int SB = (L + 1023) / 1024;

    // workspace (cnt overlays bufA: dead before k_m1 writes it)
    char* w = (char*)d_ws;
    size_t o = 0;
    float* dinv       = (float*)(w + o); o = alignup(o + (size_t)N * 4, 16);
    int* row          = (int*)(w + o);   o = alignup(o + ((size_t)N + 1) * 4, 16);
    int* bsum         = (int*)(w + o);   o = alignup(o + (size_t)SB * 4, 16);
    int* bOff         = (int*)(w + o);   o = alignup(o + ((size_t)nb + 1) * 4, 16);
    unsigned int* rec = (unsigned int*)(w + o); o = alignup(o + (size_t)E * 4, 16);
    float* bufA       = (float*)(w + o); o = alignup(o + (size_t)N * HID * 4, 16);
    float* bufB       = (float*)(w + o); o = alignup(o + (size_t)N * HID * 4, 16);
    int* cnt          = (int*)bufA;            // L*4 = 3.2MB <= bufA
    (void)ws_size;

    int blk = 256;
    int gN16 = (N * HID + blk - 1) / blk;

    // CSR build: counting-sort partition + per-bucket (dst, src-window) sort
    k_cnt<<<CHUNKS, PBLK, 0, stream>>>(dst, cnt, E, nb);
    k_scanA<<<SB, 1024, 0, stream>>>(cnt, bsum, L);
    k_scanB<<<1, 1024, 0, stream>>>(bsum, SB);
    k_scanC<<<SB, 1024, 0, stream>>>(cnt, bsum, bOff, L, nb, E);
    k_part<<<CHUNKS, PBLK, 0, stream>>>(src, dst, cnt, rec, E, nb);
    k_sort<<<nb, 256, 0, stream>>>(bOff, rec, dinv, row, N, nb, E);

    // layer 1
    k_m1<<<gN16, blk, 0, stream>>>(x, W1, dinv, bufA, N);
    k_agg1<<<nb, blk, 0, stream>>>(row, rec, dinv, (const float4*)bufA,
                                   (const float4*)b1, (float4*)bufB, N);

    // layer 2 + readout
    k_m2<<<nb, blk, 0, stream>>>((float4*)bufB, W2, dinv, N);      // bufB = mS2 in place
    k_agg2<<<nb, blk, 0, stream>>>(row, rec, dinv, (const float4*)bufB,
                                   (const float4*)b2, Wl, bl, out, N);
}

// Round 11
// 623.181 us; speedup vs baseline: 4.0401x; 1.2821x over previous
//
#include <hip/hip_runtime.h>

#define HID 16
#define OUTC 4
#define G 64             // nodes per dst-bucket
#define GSH 6            // log2(G)
#define CAP 5120         // LDS record buffer per bucket (avg 4096, +16 sigma)
#define PHSH 15          // src-phase granule: 32768 nodes = 2MB of mS (L2-resident)
#define SUBK 8           // bins per node (>= nphase)
#define KB (G * SUBK)    // 512 sort bins
#define CHUNKS 256       // edge chunks: ~16 records = 64B per count cell
#define PBLK 512         // threads per partition-pass block
#define MAXNB 4096       // max buckets supported by LDS tables (need 3125)

__device__ __forceinline__ float relu(float v) { return v > 0.f ? v : 0.f; }

// ---- Pass A: per-(bucket,chunk) counts via LDS histogram (int atomics only) ----
__global__ void k_cnt(const int* __restrict__ dst, int* __restrict__ cnt, int E, int nb) {
    __shared__ int lc[MAXNB];
    for (int i = threadIdx.x; i < nb; i += PBLK) lc[i] = 0;
    __syncthreads();
    int c = blockIdx.x;
    int chunk = (E + CHUNKS - 1) / CHUNKS;
    int lo = c * chunk, hi = lo + chunk < E ? lo + chunk : E;
    for (int i = lo + threadIdx.x; i < hi; i += PBLK)
        atomicAdd(lc + (dst[i] >> GSH), 1);
    __syncthreads();
    for (int b = threadIdx.x; b < nb; b += PBLK)
        cnt[b * CHUNKS + c] = lc[b];
}

// ---- hierarchical exclusive scan over cnt[nb*CHUNKS] ----
__global__ void k_scanA(int* __restrict__ a, int* __restrict__ bsum, int L) {
    __shared__ int s[1024];
    int i = blockIdx.x * 1024 + threadIdx.x;
    int v = (i < L) ? a[i] : 0;
    s[threadIdx.x] = v; __syncthreads();
    for (int off = 1; off < 1024; off <<= 1) {
        int t = (threadIdx.x >= (unsigned)off) ? s[threadIdx.x - off] : 0;
        __syncthreads();
        s[threadIdx.x] += t;
        __syncthreads();
    }
    if (i < L) a[i] = s[threadIdx.x] - v;               // block-local exclusive
    if (threadIdx.x == 1023) bsum[blockIdx.x] = s[1023];
}

__global__ void k_scanB(int* __restrict__ bsum, int SB) {
    __shared__ int s[1024];
    int carry = 0;
    for (int base = 0; base < SB; base += 1024) {
        int idx = base + threadIdx.x;
        int v = (idx < SB) ? bsum[idx] : 0;
        s[threadIdx.x] = v; __syncthreads();
        for (int off = 1; off < 1024; off <<= 1) {
            int t = (threadIdx.x >= (unsigned)off) ? s[threadIdx.x - off] : 0;
            __syncthreads();
            s[threadIdx.x] += t;
            __syncthreads();
        }
        if (idx < SB) bsum[idx] = carry + s[threadIdx.x] - v;   // exclusive
        carry += s[1023];
        __syncthreads();
    }
}

__global__ void k_scanC(int* __restrict__ a, const int* __restrict__ bsum,
                        int* __restrict__ bOff, int L, int nb, int E) {
    int i = blockIdx.x * 1024 + threadIdx.x;
    if (i < L) {
        int v = a[i] + bsum[blockIdx.x];
        a[i] = v;
        if ((i & (CHUNKS - 1)) == 0) bOff[i / CHUNKS] = v;
    }
    if (i == 0) bOff[nb] = E;
}

// ---- Pass B: partition into bucket regions (LDS cursors only) ----
__global__ void k_part(const int* __restrict__ src, const int* __restrict__ dst,
                       const int* __restrict__ cnt, unsigned int* __restrict__ rec,
                       int E, int nb) {
    __shared__ int cur[MAXNB];
    int c = blockIdx.x;
    for (int b = threadIdx.x; b < nb; b += PBLK) cur[b] = cnt[b * CHUNKS + c];
    __syncthreads();
    int chunk = (E + CHUNKS - 1) / CHUNKS;
    int lo = c * chunk, hi = lo + chunk < E ? lo + chunk : E;
    for (int i = lo + threadIdx.x; i < hi; i += PBLK) {
        int d = dst[i], s = src[i];
        int p = atomicAdd(cur + (d >> GSH), 1);         // LDS int atomic
        rec[p] = (unsigned int)s | ((unsigned int)(d & (G - 1)) << 18);
    }
}

// ---- per-bucket counting sort by (dst_local, src>>PHSH); emits per-phase
//      adjacency offsets rowp[n*SUBK+j] and dinv ----
__global__ void __launch_bounds__(256) k_sort(const int* __restrict__ bOff,
                                              unsigned int* __restrict__ rec,
                                              float* __restrict__ dinv,
                                              int* __restrict__ rowp,
                                              int N, int nb, int E) {
    __shared__ unsigned int raw[CAP];
    __shared__ int hist[KB], cur[KB];
    __shared__ int s[256];
    int b = blockIdx.x;
    int beg = bOff[b], end = bOff[b + 1];
    int size = end - beg; if (size > CAP) size = CAP;    // statistically impossible; LDS guard
    for (int i = threadIdx.x; i < size; i += 256) raw[i] = rec[beg + i];
    for (int k = threadIdx.x; k < KB; k += 256) hist[k] = 0;
    __syncthreads();
    for (int i = threadIdx.x; i < size; i += 256) {
        unsigned int r = raw[i];
        int key = (int)((r >> 18) << 3) | (int)((r & 0x3FFFF) >> PHSH);
        atomicAdd(hist + key, 1);                       // LDS int atomic
    }
    __syncthreads();
    // exclusive scan of hist[KB]: 256 threads x 2 bins each
    int t = threadIdx.x;
    int psum = hist[t * 2] + hist[t * 2 + 1];
    s[t] = psum; __syncthreads();
    for (int off = 1; off < 256; off <<= 1) {
        int v = (t >= off) ? s[t - off] : 0;
        __syncthreads();
        s[t] += v;
        __syncthreads();
    }
    int ex = s[t] - psum;                               // exclusive base of this thread's bins
    cur[t * 2] = ex;
    cur[t * 2 + 1] = ex + hist[t * 2];
    __syncthreads();
    // rowp + dinv (snapshot cur before scatter mutates it)
    if (t < G) {
        int n = b * G + t;
        if (n < N) {
            int deg = 0;
#pragma unroll
            for (int j = 0; j < SUBK; ++j) {
                rowp[(size_t)n * SUBK + j] = beg + cur[t * SUBK + j];
                deg += hist[t * SUBK + j];
            }
            dinv[n] = rsqrtf((float)deg + 1.0f);        // +1 self-loop
        }
    }
    __syncthreads();
    // scatter: reads LDS copy, writes into own global range (no hazard)
    for (int i = t; i < size; i += 256) {
        unsigned int r = raw[i];
        int key = (int)((r >> 18) << 3) | (int)((r & 0x3FFFF) >> PHSH);
        int p = atomicAdd(cur + key, 1);                // LDS int atomic
        rec[beg + p] = r & 0x3FFFF;                     // adjacency = src id
    }
}

// ---- mS1[n][c] = x[n] * W1[c] * dinv[n]  (IN_C == 1) ----
__global__ void k_m1(const float* __restrict__ x, const float* __restrict__ W1,
                     const float* __restrict__ dinv, float* __restrict__ m, int N) {
    int t = blockIdx.x * blockDim.x + threadIdx.x;
    if (t < N * HID) {
        int n = t >> 4, c = t & 15;
        m[t] = x[n] * W1[c] * dinv[n];
    }
}

// ---- in-place h -> (h @ W2) * dinv ----
__global__ void k_m2(float4* __restrict__ h4, const float* __restrict__ W2,
                     const float* __restrict__ dinv, int N) {
    __shared__ float hs[64][HID + 1];
    __shared__ float w[HID * HID];
    if (threadIdx.x < HID * HID) w[threadIdx.x] = W2[threadIdx.x];
    int idx = blockIdx.x * 256 + threadIdx.x;          // float4 index
    int n = idx >> 2, q = idx & 3;
    int ln = threadIdx.x >> 2;
    if (n < N) {
        float4 v = h4[idx];
        hs[ln][q * 4 + 0] = v.x; hs[ln][q * 4 + 1] = v.y;
        hs[ln][q * 4 + 2] = v.z; hs[ln][q * 4 + 3] = v.w;
    }
    __syncthreads();
    if (n < N) {
        float dn = dinv[n];
        float4 acc = make_float4(0.f, 0.f, 0.f, 0.f);
        const float* hr = hs[ln];
#pragma unroll
        for (int ci = 0; ci < HID; ++ci) {
            float hv = hr[ci];
            const float* wr = w + ci * HID + q * 4;
            acc.x += hv * wr[0]; acc.y += hv * wr[1];
            acc.z += hv * wr[2]; acc.w += hv * wr[3];
        }
        acc.x *= dn; acc.y *= dn; acc.z *= dn; acc.w *= dn;
        h4[idx] = acc;
    }
}

// ---- phased CSR aggregation: one launch per src-phase (global barrier between
//      phases keeps the 2MB mS window L2-resident chip-wide).
//      MODE 0: store partial to gagg. MODE 1: layer-1 epilogue (relu->h in gagg).
//      MODE 2: layer-2 epilogue (readout @Wl+bl -> out). ----
template <int MODE>
__global__ void __launch_bounds__(256) k_aggp(const int* __restrict__ rowp,
                                              const unsigned int* __restrict__ adj,
                                              const float* __restrict__ dinv,
                                              const float4* __restrict__ mS4,
                                              float4* __restrict__ gagg4,
                                              const float4* __restrict__ b4,
                                              const float* __restrict__ Wl,
                                              const float* __restrict__ bl,
                                              float* __restrict__ out,
                                              int N, int p) {
    __shared__ float hs[G][HID + 1];
    __shared__ float wl[HID * OUTC];
    __shared__ float blv[OUTC];
    if (MODE == 2) {
        if (threadIdx.x < HID * OUTC) wl[threadIdx.x] = Wl[threadIdx.x];
        if (threadIdx.x < OUTC) blv[threadIdx.x] = bl[threadIdx.x];
    }
    int dl = threadIdx.x >> 2, q = threadIdx.x & 3;
    int n = blockIdx.x * G + dl;
    if (n < N) {
        int i = rowp[(size_t)n * SUBK + p];
        int end = rowp[(size_t)n * SUBK + p + 1];
        float4 acc = (p == 0) ? mS4[n * 4 + q] : gagg4[n * 4 + q];  // p0: self-loop init
        for (; i + 4 <= end; i += 4) {                  // 4 independent gathers in flight
            int s0 = adj[i] * 4 + q, s1 = adj[i + 1] * 4 + q;
            int s2 = adj[i + 2] * 4 + q, s3 = adj[i + 3] * 4 + q;
            float4 v0 = mS4[s0], v1 = mS4[s1], v2 = mS4[s2], v3 = mS4[s3];
            acc.x += v0.x + v1.x + v2.x + v3.x;
            acc.y += v0.y + v1.y + v2.y + v3.y;
            acc.z += v0.z + v1.z + v2.z + v3.z;
            acc.w += v0.w + v1.w + v2.w + v3.w;
        }
        for (; i < end; ++i) {
            float4 v = mS4[adj[i] * 4 + q];
            acc.x += v.x; acc.y += v.y; acc.z += v.z; acc.w += v.w;
        }
        if (MODE == 0) {
            gagg4[n * 4 + q] = acc;
        } else {
            float dn = dinv[n];
            float4 bb = b4[q];
            float4 h;
            h.x = relu(acc.x * dn + bb.x);
            h.y = relu(acc.y * dn + bb.y);
            h.z = relu(acc.z * dn + bb.z);
            h.w = relu(acc.w * dn + bb.w);
            if (MODE == 1) {
                gagg4[n * 4 + q] = h;                   // h written in place of gagg
            } else {
                hs[dl][q * 4 + 0] = h.x; hs[dl][q * 4 + 1] = h.y;
                hs[dl][q * 4 + 2] = h.z; hs[dl][q * 4 + 3] = h.w;
            }
        }
    }
    if (MODE == 2) {
        __syncthreads();
        if (n < N) {   // thread -> (node dl, out-channel q)
            float acc = blv[q];
            const float* hr = hs[dl];
#pragma unroll
            for (int ci = 0; ci < HID; ++ci) acc += hr[ci] * wl[ci * OUTC + q];
            out[n * OUTC + q] = acc;
        }
    }
}

// ---------- launch ----------
static inline size_t alignup(size_t v, size_t a) { return (v + a - 1) & ~(a - 1); }

extern "C" void kernel_launch(void* const* d_in, const int* in_sizes, int n_in,
                              void* d_out, int out_size, void* d_ws, size_t ws_size,
                              hipStream_t stream) {
    const float* x  = (const float*)d_in[0];
    const int* ed   = (const int*)d_in[1];     // int inputs delivered as int32
    const float* W1 = (const float*)d_in[2];
    const float* b1 = (const float*)d_in[3];
    const float* W2 = (const float*)d_in[4];
    const float* b2 = (const float*)d_in[5];
    const float* Wl = (const float*)d_in[6];
    const float* bl = (const float*)d_in[7];
    float* out      = (float*)d_out;

    int N = in_sizes[0];
    int E = in_sizes[1] / 2;
    const int* src = ed;
    const int* dst = ed + E;
    int nb = (N + G - 1) / G;                  // 3125 buckets (<= MAXNB)
    int L = nb * CHUNKS;                       // 800K count cells
    int SB = (L + 1023) / 1024;
    int nphase = (N + (1 << PHSH) - 1) >> PHSH;   // 7 (<= SUBK)

    // workspace (cnt overlays bufA: dead before k_m1 writes it)
    char* w = (char*)d_ws;
    size_t o = 0;
    float* dinv       = (float*)(w + o); o = alignup(o + (size_t)N * 4, 16);
    int* rowp         = (int*)(w + o);   o = alignup(o + (size_t)N * SUBK * 4, 16);
    int* bsum         = (int*)(w + o);   o = alignup(o + (size_t)SB * 4, 16);
    int* bOff         = (int*)(w + o);   o = alignup(o + ((size_t)nb + 1) * 4, 16);
    unsigned int* rec = (unsigned int*)(w + o); o = alignup(o + (size_t)E * 4, 16);
    float* bufA       = (float*)(w + o); o = alignup(o + (size_t)N * HID * 4, 16);
    float* bufB       = (float*)(w + o); o = alignup(o + (size_t)N * HID * 4, 16);
    int* cnt          = (int*)bufA;            // L*4 = 3.2MB <= bufA
    (void)ws_size;

    int blk = 256;
    int gN16 = (N * HID + blk - 1) / blk;

    // CSR build: counting-sort partition + per-bucket (dst, src-phase) sort
    k_cnt<<<CHUNKS, PBLK, 0, stream>>>(dst, cnt, E, nb);
    k_scanA<<<SB, 1024, 0, stream>>>(cnt, bsum, L);
    k_scanB<<<1, 1024, 0, stream>>>(bsum, SB);
    k_scanC<<<SB, 1024, 0, stream>>>(cnt, bsum, bOff, L, nb, E);
    k_part<<<CHUNKS, PBLK, 0, stream>>>(src, dst, cnt, rec, E, nb);
    k_sort<<<nb, 256, 0, stream>>>(bOff, rec, dinv, rowp, N, nb, E);

    // layer 1: mS1 in bufA, gagg/h1 in bufB
    k_m1<<<gN16, blk, 0, stream>>>(x, W1, dinv, bufA, N);
    for (int p = 0; p < nphase; ++p) {
        if (p < nphase - 1)
            k_aggp<0><<<nb, blk, 0, stream>>>(rowp, rec, dinv, (const float4*)bufA,
                                              (float4*)bufB, (const float4*)b1,
                                              nullptr, nullptr, nullptr, N, p);
        else
            k_aggp<1><<<nb, blk, 0, stream>>>(rowp, rec, dinv, (const float4*)bufA,
                                              (float4*)bufB, (const float4*)b1,
                                              nullptr, nullptr, nullptr, N, p);
    }

    // layer 2: mS2 in bufB (in place), gagg in bufA, readout fused into last phase
    k_m2<<<nb, blk, 0, stream>>>((float4*)bufB, W2, dinv, N);
    for (int p = 0; p < nphase; ++p) {
        if (p < nphase - 1)
            k_aggp<0><<<nb, blk, 0, stream>>>(rowp, rec, dinv, (const float4*)bufB,
                                              (float4*)bufA, (const float4*)b2,
                                              nullptr, nullptr, nullptr, N, p);
        else
            k_aggp<2><<<nb, blk, 0, stream>>>(rowp, rec, dinv, (const float4*)bufB,
                                              (float4*)bufA, (const float4*)b2,
                                              Wl, bl, out, N, p);
    }
}

// Round 12
// 622.046 us; speedup vs baseline: 4.0474x; 1.0018x over previous
//
#include <hip/hip_runtime.h>

#define HID 16
#define OUTC 4
#define G 64             // nodes per agg block
#define SBSH 8           // 256 nodes per partition/sort bucket
#define SBN 256          // nodes per sort bucket
#define CAP 17408        // LDS record buffer per sort bucket (mean 16384, +8 sigma)
#define PHSH 15          // src-phase granule: 32768 nodes = 2MB of mS (L2-resident)
#define SUBK 8           // bins per node (>= nphase)
#define KB (SBN * SUBK)  // 2048 sort bins
#define CHUNKS 256       // edge chunks for partition passes
#define PBLK 512         // threads per partition-pass block
#define NPB_MAX 1024     // max partition buckets in LDS tables (need 782)

__device__ __forceinline__ float relu(float v) { return v > 0.f ? v : 0.f; }

// ---- Pass A: per-(bucket,chunk) counts via LDS histogram (int atomics only) ----
__global__ void k_cnt(const int* __restrict__ dst, int* __restrict__ cnt, int E, int nsb) {
    __shared__ int lc[NPB_MAX];
    for (int i = threadIdx.x; i < nsb; i += PBLK) lc[i] = 0;
    __syncthreads();
    int c = blockIdx.x;
    int chunk = (E + CHUNKS - 1) / CHUNKS;
    int lo = c * chunk, hi = lo + chunk < E ? lo + chunk : E;
    for (int i = lo + threadIdx.x; i < hi; i += PBLK)
        atomicAdd(lc + (dst[i] >> SBSH), 1);
    __syncthreads();
    for (int b = threadIdx.x; b < nsb; b += PBLK)
        cnt[b * CHUNKS + c] = lc[b];
}

// ---- hierarchical exclusive scan over cnt[nsb*CHUNKS] ----
__global__ void k_scanA(int* __restrict__ a, int* __restrict__ bsum, int L) {
    __shared__ int s[1024];
    int i = blockIdx.x * 1024 + threadIdx.x;
    int v = (i < L) ? a[i] : 0;
    s[threadIdx.x] = v; __syncthreads();
    for (int off = 1; off < 1024; off <<= 1) {
        int t = (threadIdx.x >= (unsigned)off) ? s[threadIdx.x - off] : 0;
        __syncthreads();
        s[threadIdx.x] += t;
        __syncthreads();
    }
    if (i < L) a[i] = s[threadIdx.x] - v;               // block-local exclusive
    if (threadIdx.x == 1023) bsum[blockIdx.x] = s[1023];
}

__global__ void k_scanB(int* __restrict__ bsum, int SB) {
    __shared__ int s[1024];
    int carry = 0;
    for (int base = 0; base < SB; base += 1024) {
        int idx = base + threadIdx.x;
        int v = (idx < SB) ? bsum[idx] : 0;
        s[threadIdx.x] = v; __syncthreads();
        for (int off = 1; off < 1024; off <<= 1) {
            int t = (threadIdx.x >= (unsigned)off) ? s[threadIdx.x - off] : 0;
            __syncthreads();
            s[threadIdx.x] += t;
            __syncthreads();
        }
        if (idx < SB) bsum[idx] = carry + s[threadIdx.x] - v;   // exclusive
        carry += s[1023];
        __syncthreads();
    }
}

__global__ void k_scanC(int* __restrict__ a, const int* __restrict__ bsum,
                        int* __restrict__ bOff, int L, int nsb, int E) {
    int i = blockIdx.x * 1024 + threadIdx.x;
    if (i < L) {
        int v = a[i] + bsum[blockIdx.x];
        a[i] = v;
        if ((i & (CHUNKS - 1)) == 0) bOff[i / CHUNKS] = v;
    }
    if (i == 0) bOff[nsb] = E;
}

// ---- Pass B: partition into 256-node bucket regions (782 streams; L2-mergeable) ----
__global__ void k_part(const int* __restrict__ src, const int* __restrict__ dst,
                       const int* __restrict__ cnt, unsigned int* __restrict__ rec,
                       int E, int nsb) {
    __shared__ int cur[NPB_MAX];
    int c = blockIdx.x;
    for (int b = threadIdx.x; b < nsb; b += PBLK) cur[b] = cnt[b * CHUNKS + c];
    __syncthreads();
    int chunk = (E + CHUNKS - 1) / CHUNKS;
    int lo = c * chunk, hi = lo + chunk < E ? lo + chunk : E;
    for (int i = lo + threadIdx.x; i < hi; i += PBLK) {
        int d = dst[i], s = src[i];
        int p = atomicAdd(cur + (d >> SBSH), 1);        // LDS int atomic
        rec[p] = (unsigned int)s | ((unsigned int)(d & (SBN - 1)) << 18);
    }
}

// ---- per-bucket counting sort by (dst_local, src>>PHSH); emits per-phase
//      adjacency offsets rowp[n*SUBK+j] and dinv. One 256-node bucket per block. ----
__global__ void __launch_bounds__(256) k_sort(const int* __restrict__ bOff,
                                              unsigned int* __restrict__ rec,
                                              float* __restrict__ dinv,
                                              int* __restrict__ rowp,
                                              int N, int nsb, int E) {
    __shared__ unsigned int raw[CAP];
    __shared__ int hist[KB], cur[KB];
    __shared__ int s[256];
    int b = blockIdx.x;
    int beg = bOff[b], end = bOff[b + 1];
    int size = end - beg; if (size > CAP) size = CAP;    // statistically impossible; LDS guard
    for (int i = threadIdx.x; i < size; i += 256) raw[i] = rec[beg + i];
    for (int k = threadIdx.x; k < KB; k += 256) hist[k] = 0;
    __syncthreads();
    for (int i = threadIdx.x; i < size; i += 256) {
        unsigned int r = raw[i];
        int key = (int)((r >> 18) << 3) | (int)((r & 0x3FFFF) >> PHSH);
        atomicAdd(hist + key, 1);                       // LDS int atomic
    }
    __syncthreads();
    // exclusive scan of hist[KB]: thread t owns node t's 8 bins
    int t = threadIdx.x;
    int psum = 0;
#pragma unroll
    for (int j = 0; j < SUBK; ++j) psum += hist[t * SUBK + j];
    s[t] = psum; __syncthreads();
    for (int off = 1; off < 256; off <<= 1) {
        int v = (t >= off) ? s[t - off] : 0;
        __syncthreads();
        s[t] += v;
        __syncthreads();
    }
    int ex = s[t] - psum;                               // exclusive base of node t's bins
    {
        int n = b * SBN + t;
        bool valid = (n < N);
        int running = ex;
#pragma unroll
        for (int j = 0; j < SUBK; ++j) {
            cur[t * SUBK + j] = running;
            if (valid) rowp[(size_t)n * SUBK + j] = beg + running;
            running += hist[t * SUBK + j];
        }
        if (valid) dinv[n] = rsqrtf((float)psum + 1.0f);    // +1 self-loop
    }
    __syncthreads();
    // scatter: reads LDS copy, writes into own global range (no hazard)
    for (int i = t; i < size; i += 256) {
        unsigned int r = raw[i];
        int key = (int)((r >> 18) << 3) | (int)((r & 0x3FFFF) >> PHSH);
        int p = atomicAdd(cur + key, 1);                // LDS int atomic
        rec[beg + p] = r & 0x3FFFF;                     // adjacency = src id
    }
}

// ---- mS1[n][c] = x[n] * W1[c] * dinv[n]  (IN_C == 1) ----
__global__ void k_m1(const float* __restrict__ x, const float* __restrict__ W1,
                     const float* __restrict__ dinv, float* __restrict__ m, int N) {
    int t = blockIdx.x * blockDim.x + threadIdx.x;
    if (t < N * HID) {
        int n = t >> 4, c = t & 15;
        m[t] = x[n] * W1[c] * dinv[n];
    }
}

// ---- in-place h -> (h @ W2) * dinv ----
__global__ void k_m2(float4* __restrict__ h4, const float* __restrict__ W2,
                     const float* __restrict__ dinv, int N) {
    __shared__ float hs[64][HID + 1];
    __shared__ float w[HID * HID];
    if (threadIdx.x < HID * HID) w[threadIdx.x] = W2[threadIdx.x];
    int idx = blockIdx.x * 256 + threadIdx.x;          // float4 index
    int n = idx >> 2, q = idx & 3;
    int ln = threadIdx.x >> 2;
    if (n < N) {
        float4 v = h4[idx];
        hs[ln][q * 4 + 0] = v.x; hs[ln][q * 4 + 1] = v.y;
        hs[ln][q * 4 + 2] = v.z; hs[ln][q * 4 + 3] = v.w;
    }
    __syncthreads();
    if (n < N) {
        float dn = dinv[n];
        float4 acc = make_float4(0.f, 0.f, 0.f, 0.f);
        const float* hr = hs[ln];
#pragma unroll
        for (int ci = 0; ci < HID; ++ci) {
            float hv = hr[ci];
            const float* wr = w + ci * HID + q * 4;
            acc.x += hv * wr[0]; acc.y += hv * wr[1];
            acc.z += hv * wr[2]; acc.w += hv * wr[3];
        }
        acc.x *= dn; acc.y *= dn; acc.z *= dn; acc.w *= dn;
        h4[idx] = acc;
    }
}

// ---- phased CSR aggregation: one launch per src-phase (global barrier between
//      phases keeps the 2MB mS window L2-resident chip-wide).
//      MODE 0: store partial to gagg. MODE 1: layer-1 epilogue (relu->h in gagg).
//      MODE 2: layer-2 epilogue (readout @Wl+bl -> out). ----
template <int MODE>
__global__ void __launch_bounds__(256) k_aggp(const int* __restrict__ rowp,
                                              const unsigned int* __restrict__ adj,
                                              const float* __restrict__ dinv,
                                              const float4* __restrict__ mS4,
                                              float4* __restrict__ gagg4,
                                              const float4* __restrict__ b4,
                                              const float* __restrict__ Wl,
                                              const float* __restrict__ bl,
                                              float* __restrict__ out,
                                              int N, int p) {
    __shared__ float hs[G][HID + 1];
    __shared__ float wl[HID * OUTC];
    __shared__ float blv[OUTC];
    if (MODE == 2) {
        if (threadIdx.x < HID * OUTC) wl[threadIdx.x] = Wl[threadIdx.x];
        if (threadIdx.x < OUTC) blv[threadIdx.x] = bl[threadIdx.x];
    }
    int dl = threadIdx.x >> 2, q = threadIdx.x & 3;
    int n = blockIdx.x * G + dl;
    if (n < N) {
        int i = rowp[(size_t)n * SUBK + p];
        int end = rowp[(size_t)n * SUBK + p + 1];
        float4 acc = (p == 0) ? mS4[n * 4 + q] : gagg4[n * 4 + q];  // p0: self-loop init
        for (; i + 4 <= end; i += 4) {                  // 4 independent gathers in flight
            int s0 = adj[i] * 4 + q, s1 = adj[i + 1] * 4 + q;
            int s2 = adj[i + 2] * 4 + q, s3 = adj[i + 3] * 4 + q;
            float4 v0 = mS4[s0], v1 = mS4[s1], v2 = mS4[s2], v3 = mS4[s3];
            acc.x += v0.x + v1.x + v2.x + v3.x;
            acc.y += v0.y + v1.y + v2.y + v3.y;
            acc.z += v0.z + v1.z + v2.z + v3.z;
            acc.w += v0.w + v1.w + v2.w + v3.w;
        }
        for (; i < end; ++i) {
            float4 v = mS4[adj[i] * 4 + q];
            acc.x += v.x; acc.y += v.y; acc.z += v.z; acc.w += v.w;
        }
        if (MODE == 0) {
            gagg4[n * 4 + q] = acc;
        } else {
            float dn = dinv[n];
            float4 bb = b4[q];
            float4 h;
            h.x = relu(acc.x * dn + bb.x);
            h.y = relu(acc.y * dn + bb.y);
            h.z = relu(acc.z * dn + bb.z);
            h.w = relu(acc.w * dn + bb.w);
            if (MODE == 1) {
                gagg4[n * 4 + q] = h;                   // h written in place of gagg
            } else {
                hs[dl][q * 4 + 0] = h.x; hs[dl][q * 4 + 1] = h.y;
                hs[dl][q * 4 + 2] = h.z; hs[dl][q * 4 + 3] = h.w;
            }
        }
    }
    if (MODE == 2) {
        __syncthreads();
        if (n < N) {   // thread -> (node dl, out-channel q)
            float acc = blv[q];
            const float* hr = hs[dl];
#pragma unroll
            for (int ci = 0; ci < HID; ++ci) acc += hr[ci] * wl[ci * OUTC + q];
            out[n * OUTC + q] = acc;
        }
    }
}

// ---------- launch ----------
static inline size_t alignup(size_t v, size_t a) { return (v + a - 1) & ~(a - 1); }

extern "C" void kernel_launch(void* const* d_in, const int* in_sizes, int n_in,
                              void* d_out, int out_size, void* d_ws, size_t ws_size,
                              hipStream_t stream) {
    const float* x  = (const float*)d_in[0];
    const int* ed   = (const int*)d_in[1];     // int inputs delivered as int32
    const float* W1 = (const float*)d_in[2];
    const float* b1 = (const float*)d_in[3];
    const float* W2 = (const float*)d_in[4];
    const float* b2 = (const float*)d_in[5];
    const float* Wl = (const float*)d_in[6];
    const float* bl = (const float*)d_in[7];
    float* out      = (float*)d_out;

    int N = in_sizes[0];
    int E = in_sizes[1] / 2;
    const int* src = ed;
    const int* dst = ed + E;
    int nsb = (N + SBN - 1) / SBN;             // 782 partition/sort buckets
    int nb64 = (N + G - 1) / G;                // 3125 agg blocks
    int L = nsb * CHUNKS;                      // 200K count cells
    int SB = (L + 1023) / 1024;
    int nphase = (N + (1 << PHSH) - 1) >> PHSH;   // 7 (<= SUBK)

    // workspace (cnt overlays bufA: dead before k_m1 writes it)
    char* w = (char*)d_ws;
    size_t o = 0;
    float* dinv       = (float*)(w + o); o = alignup(o + (size_t)N * 4, 16);
    int* rowp         = (int*)(w + o);   o = alignup(o + (size_t)N * SUBK * 4, 16);
    int* bsum         = (int*)(w + o);   o = alignup(o + (size_t)SB * 4, 16);
    int* bOff         = (int*)(w + o);   o = alignup(o + ((size_t)nsb + 1) * 4, 16);
    unsigned int* rec = (unsigned int*)(w + o); o = alignup(o + (size_t)E * 4, 16);
    float* bufA       = (float*)(w + o); o = alignup(o + (size_t)N * HID * 4, 16);
    float* bufB       = (float*)(w + o); o = alignup(o + (size_t)N * HID * 4, 16);
    int* cnt          = (int*)bufA;            // L*4 = 800KB <= bufA
    (void)ws_size;

    int blk = 256;
    int gN16 = (N * HID + blk - 1) / blk;

    // CSR build: coarse counting-sort partition + per-bucket (dst_local, phase) sort
    k_cnt<<<CHUNKS, PBLK, 0, stream>>>(dst, cnt, E, nsb);
    k_scanA<<<SB, 1024, 0, stream>>>(cnt, bsum, L);
    k_scanB<<<1, 1024, 0, stream>>>(bsum, SB);
    k_scanC<<<SB, 1024, 0, stream>>>(cnt, bsum, bOff, L, nsb, E);
    k_part<<<CHUNKS, PBLK, 0, stream>>>(src, dst, cnt, rec, E, nsb);
    k_sort<<<nsb, 256, 0, stream>>>(bOff, rec, dinv, rowp, N, nsb, E);

    // layer 1: mS1 in bufA, gagg/h1 in bufB
    k_m1<<<gN16, blk, 0, stream>>>(x, W1, dinv, bufA, N);
    for (int p = 0; p < nphase; ++p) {
        if (p < nphase - 1)
            k_aggp<0><<<nb64, blk, 0, stream>>>(rowp, rec, dinv, (const float4*)bufA,
                                                (float4*)bufB, (const float4*)b1,
                                                nullptr, nullptr, nullptr, N, p);
        else
            k_aggp<1><<<nb64, blk, 0, stream>>>(rowp, rec, dinv, (const float4*)bufA,
                                                (float4*)bufB, (const float4*)b1,
                                                nullptr, nullptr, nullptr, N, p);
    }

    // layer 2: mS2 in bufB (in place), gagg in bufA, readout fused into last phase
    k_m2<<<nb64, blk, 0, stream>>>((float4*)bufB, W2, dinv, N);
    for (int p = 0; p < nphase; ++p) {
        if (p < nphase - 1)
            k_aggp<0><<<nb64, blk, 0, stream>>>(rowp, rec, dinv, (const float4*)bufB,
                                                (float4*)bufA, (const float4*)b2,
                                                nullptr, nullptr, nullptr, N, p);
        else
            k_aggp<2><<<nb64, blk, 0, stream>>>(rowp, rec, dinv, (const float4*)bufB,
                                                (float4*)bufA, (const float4*)b2,
                                                Wl, bl, out, N, p);
    }
}